// Round 7
// baseline (222.818 us; speedup 1.0000x reference)
//
#include <hip/hip_runtime.h>
#include <math.h>

#define BATCH 32
#define HIN   224
#define WIN   224
#define CIN   3
#define KOUT  64
#define RK    5
#define HOUT  220
#define WOUT  220

#define TS     16                 // output tile: 16x16 pixels
#define PATCH  20
#define NTOT ((size_t)BATCH * HOUT * WOUT * KOUT)

typedef float  v4f    __attribute__((ext_vector_type(4)));
typedef short  short8 __attribute__((ext_vector_type(8)));   // 8 bf16 = 4 VGPRs

// d_ws layout: [0,12288): 768 x short8 weight frags  [12288,12544): 64 f32 softplus(w_sigma)
#define WS_WF_FRAGS 768
#define WS_WSG_OFF  12288

// --- HW transcendentals: v_exp_f32 = 2^x, v_log_f32 = log2(x) ---
__device__ __forceinline__ float exp2_hw(float x) { float r; asm("v_exp_f32 %0, %1" : "=v"(r) : "v"(x)); return r; }
__device__ __forceinline__ float log2_hw(float x) { float r; asm("v_log_f32 %0, %1" : "=v"(r) : "v"(x)); return r; }
#define LOG2E 1.44269504088896f
#define LN2   0.69314718055995f

__device__ __forceinline__ float softplus_hw(float x) {       // general, stable
    float t = exp2_hw(-fabsf(x) * LOG2E);
    return fmaxf(x, 0.0f) + LN2 * log2_hw(1.0f + t);
}
__device__ __forceinline__ float softplus_pos(float y) {      // y >= 0 fast path
    return y + LN2 * log2_hw(1.0f + exp2_hw(-y * LOG2E));
}
__device__ __forceinline__ short f2bf(float x) {              // f32 -> bf16 bits, RNE
    unsigned u = __float_as_uint(x);
    u = (u + 0x7FFFu + ((u >> 16) & 1u)) >> 16;
    return (short)u;
}

// ---- prep: pack weight MFMA fragments (bf16) + softplus(w_sigma) + KL ----
// A-frag (16x16x32, M=16 ch): row = lane&15, k = (lane>>4)*8 + i.
// k-order: k = kh*16 + (kw*3 + c); inner==15 and k>=80 are zero pads.
__global__ __launch_bounds__(256) void vdp_prep_kernel(
    const float* __restrict__ w_mu, const float* __restrict__ w_sigma,
    void* __restrict__ ws, float* __restrict__ out)
{
    __shared__ float red[4];
    short8* wf = (short8*)ws;
    float* wsg = (float*)((char*)ws + WS_WSG_OFF);
    const int t = threadIdx.x;

    for (int f = t; f < WS_WF_FRAGS; f += 256) {   // f = (s*4+nb)*64 + lane
        const int s  = f >> 8;
        const int nb = (f >> 6) & 3;
        const int l  = f & 63;
        const int ch = nb * 16 + (l & 15);
        const int h2 = l >> 4;
        short8 r;
        #pragma unroll
        for (int i = 0; i < 8; ++i) {
            const int k = s * 32 + h2 * 8 + i;
            const int kh = k >> 4, inner = k & 15;
            float v = 0.0f;
            if (inner < 15 && k < 80) {
                const int kw = inner / 3;
                const int c  = inner - kw * 3;
                v = w_mu[((kh * 5 + kw) * 3 + c) * KOUT + ch];
            }
            r[i] = f2bf(v);
        }
        wf[f] = r;
    }
    if (t < KOUT) wsg[t] = softplus_hw(w_sigma[t]);

    // ---- KL scalar ----
    float s = 0.0f;
    for (int i = t; i < RK * RK * CIN * KOUT; i += 256) {
        const float v = w_mu[i];
        s = fmaf(v, v, s);
    }
    float u = s * (100.0f / 4800.0f);
    if (t < KOUT) {
        const float wsv = w_sigma[t];
        u += (-wsv + softplus_hw(wsv) * 100.0f) * (1.0f / 64.0f);
    }
    #pragma unroll
    for (int off = 32; off > 0; off >>= 1)
        u += __shfl_down(u, off, 64);
    if ((t & 63) == 0) red[t >> 6] = u;
    __syncthreads();
    if (t == 0) {
        const float U = red[0] + red[1] + red[2] + red[3];
        out[2 * NTOT] = 0.5f * (-4.6051701860f - 1.0f + U);
    }
}

// ---- conv: block = 16x16 output px; wave = 4 rows; frags in LDS ----
__global__ __launch_bounds__(256, 6) void vdp_conv_kernel(
    const float* __restrict__ mu_in, const void* __restrict__ ws, float* __restrict__ out)
{
    __shared__ float  s_row[PATCH][64];    // 20 rows x (60 valid + 4 zero) f32  (5 KB)
    __shared__ float  s_ssq[PATCH][PATCH]; // per-pixel sum_c x^2                (1.6 KB)
    __shared__ float  s_sq[TS * TS];       // 5x5 box mean                       (1 KB)
    __shared__ short8 s_wf[WS_WF_FRAGS];   // weight frags                       (12 KB)

    const int tid  = threadIdx.x;
    const int lane = tid & 63;
    const int wid  = tid >> 6;
    const int p    = lane & 15;            // MFMA: pixel col; sigma: ch-group kg
    const int h2   = lane >> 4;            // MFMA: k subgroup;  sigma: px-in-quad

    const int b = blockIdx.z;
    int ho0 = blockIdx.y * TS; if (ho0 > HOUT - TS) ho0 = HOUT - TS;  // overlap recompute
    int wo0 = blockIdx.x * TS; if (wo0 > WOUT - TS) wo0 = WOUT - TS;

    // ---- stage weight frags to LDS (coalesced dwordx4 copy; L2/L3-hot) ----
    const short8* wfg = (const short8*)ws;
    for (int f = tid; f < WS_WF_FRAGS; f += 256) s_wf[f] = wfg[f];

    const float* wsg_g = (const float*)((const char*)ws + WS_WSG_OFF);
    const v4f wsg_kg = *(const v4f*)(wsg_g + p * 4);   // sigma: ch = 4*kg..+3

    // ---- stage 20 input rows (cols 60..63 zeroed) ----
    for (int idx = tid; idx < PATCH * 64; idx += 256) {
        const int r = idx >> 6, c = idx & 63;
        float v = 0.0f;
        if (c < 60) v = mu_in[(((size_t)b * HIN + ho0 + r) * WIN + wo0) * CIN + c];
        s_row[r][c] = v;
    }
    __syncthreads();

    // ---- per-pixel channel-summed squares ----
    for (int idx = tid; idx < PATCH * PATCH; idx += 256) {
        const int r = idx / PATCH;
        const int px = idx - r * PATCH;
        const float x0 = s_row[r][3 * px], x1 = s_row[r][3 * px + 1], x2 = s_row[r][3 * px + 2];
        s_ssq[r][px] = fmaf(x0, x0, fmaf(x1, x1, x2 * x2));
    }
    __syncthreads();

    // ---- 5x5 box mean (one thread per tile pixel) ----
    {
        const int pr = tid >> 4, pc = tid & 15;
        float acc = 0.0f;
        #pragma unroll
        for (int kh = 0; kh < RK; ++kh)
            #pragma unroll
            for (int kw = 0; kw < RK; ++kw)
                acc += s_ssq[pr + kh][pc + kw];
        s_sq[tid] = acc * (1.0f / 75.0f);
    }
    __syncthreads();

    // ---- main: each wave computes 4 output rows x 16 px x 64 ch ----
    #pragma unroll 1
    for (int j = 0; j < 4; ++j) {
        const int rt = (wid << 2) | j;
        const size_t rowbase = (((size_t)b * HOUT + ho0 + rt) * WOUT + wo0) * KOUT;

        // B-frags: lane holds patch[k = s*32 + h2*8 + i][px = p]
        short8 pf[3];
        #pragma unroll
        for (int s = 0; s < 3; ++s) {
            int ridx = rt + 2 * s + (h2 >> 1);
            ridx = ridx > PATCH - 1 ? PATCH - 1 : ridx;   // k>=80 pad: garbage x 0-weight
            const float* rp = &s_row[ridx][3 * p + 8 * (h2 & 1)];
            short8 r;
            #pragma unroll
            for (int i = 0; i < 8; ++i) r[i] = f2bf(rp[i]);
            pf[s] = r;
        }

        v4f acc[4];
        #pragma unroll
        for (int nb = 0; nb < 4; ++nb) {
            v4f a = {0.0f, 0.0f, 0.0f, 0.0f};
            #pragma unroll
            for (int s = 0; s < 3; ++s)
                a = __builtin_amdgcn_mfma_f32_16x16x32_bf16(s_wf[(s * 4 + nb) * 64 + lane], pf[s], a, 0, 0, 0);
            acc[nb] = a;
        }

        // mu: D col = pixel p, rows = 4 ch at nb*16 + h2*4
        float* mp = out + rowbase + (size_t)p * KOUT + h2 * 4;
        #pragma unroll
        for (int nb = 0; nb < 4; ++nb)
            *(v4f*)(mp + nb * 16) = acc[nb];

        // sigma: kg-layout -> contiguous 1KB wave-stores
        float* sp = out + NTOT + rowbase + p * 4;   // p = kg here
        #pragma unroll
        for (int pp = 0; pp < 4; ++pp) {
            const int px = (h2 << 2) | pp;          // h2 = px quad
            const float sq = s_sq[(rt << 4) | px];
            v4f sg;
            sg.x = softplus_pos(wsg_kg.x * sq);
            sg.y = softplus_pos(wsg_kg.y * sq);
            sg.z = softplus_pos(wsg_kg.z * sq);
            sg.w = softplus_pos(wsg_kg.w * sq);
            *(v4f*)(sp + (size_t)px * KOUT) = sg;
        }
    }
}

extern "C" void kernel_launch(void* const* d_in, const int* in_sizes, int n_in,
                              void* d_out, int out_size, void* d_ws, size_t ws_size,
                              hipStream_t stream)
{
    (void)in_sizes; (void)n_in; (void)ws_size; (void)out_size;
    const float* mu_in   = (const float*)d_in[0];
    const float* w_mu    = (const float*)d_in[1];
    const float* w_sigma = (const float*)d_in[2];
    float* out = (float*)d_out;

    vdp_prep_kernel<<<1, 256, 0, stream>>>(w_mu, w_sigma, d_ws, out);
    dim3 grid((WOUT + TS - 1) / TS, (HOUT + TS - 1) / TS, BATCH);  // 14 x 14 x 32
    vdp_conv_kernel<<<grid, 256, 0, stream>>>(mu_in, d_ws, out);
}

// Round 8
// 198.052 us; speedup vs baseline: 1.1250x; 1.1250x over previous
//
#include <hip/hip_runtime.h>
#include <math.h>

#define BATCH 32
#define HIN   224
#define WIN   224
#define CIN   3
#define KOUT  64
#define RK    5
#define HOUT  220
#define WOUT  220

#define TH     16                 // tile: 16 output rows
#define TW     32                 // x 32 output px
#define PATCH_H (TH + RK - 1)     // 20
#define PATCH_W (TW + RK - 1)     // 36
#define SROW_F  112               // padded staged-row floats (36*3=108 valid)
#define NTOT ((size_t)BATCH * HOUT * WOUT * KOUT)

typedef float  v4f    __attribute__((ext_vector_type(4)));
typedef short  short8 __attribute__((ext_vector_type(8)));   // 8 bf16 = 4 VGPRs

// d_ws layout: [0,12288): 768 x short8 weight frags  [12288,12544): 64 f32 softplus(w_sigma)
#define WS_WF_FRAGS 768
#define WS_WSG_OFF  12288

// --- HW transcendentals: v_exp_f32 = 2^x, v_log_f32 = log2(x) ---
__device__ __forceinline__ float exp2_hw(float x) { float r; asm("v_exp_f32 %0, %1" : "=v"(r) : "v"(x)); return r; }
__device__ __forceinline__ float log2_hw(float x) { float r; asm("v_log_f32 %0, %1" : "=v"(r) : "v"(x)); return r; }
#define LOG2E 1.44269504088896f
#define LN2   0.69314718055995f

__device__ __forceinline__ float softplus_hw(float x) {       // general, stable
    float t = exp2_hw(-fabsf(x) * LOG2E);
    return fmaxf(x, 0.0f) + LN2 * log2_hw(1.0f + t);
}
__device__ __forceinline__ float softplus_pos(float y) {      // y >= 0 fast path
    return y + LN2 * log2_hw(1.0f + exp2_hw(-y * LOG2E));
}
__device__ __forceinline__ short f2bf(float x) {              // f32 -> bf16 bits, RNE
    unsigned u = __float_as_uint(x);
    u = (u + 0x7FFFu + ((u >> 16) & 1u)) >> 16;
    return (short)u;
}

// ---- prep: pack weight MFMA fragments (bf16) + softplus(w_sigma) + KL ----
// A-frag (16x16x32, M=16 ch): row = lane&15, k = (lane>>4)*8 + i.
// k-order: k = kh*16 + (kw*3 + c); inner==15 and k>=80 are zero pads.
__global__ __launch_bounds__(256) void vdp_prep_kernel(
    const float* __restrict__ w_mu, const float* __restrict__ w_sigma,
    void* __restrict__ ws, float* __restrict__ out)
{
    __shared__ float red[4];
    short8* wf = (short8*)ws;
    float* wsg = (float*)((char*)ws + WS_WSG_OFF);
    const int t = threadIdx.x;

    for (int f = t; f < WS_WF_FRAGS; f += 256) {   // f = (s*4+nb)*64 + lane
        const int s  = f >> 8;
        const int nb = (f >> 6) & 3;
        const int l  = f & 63;
        const int ch = nb * 16 + (l & 15);
        const int h2 = l >> 4;
        short8 r;
        #pragma unroll
        for (int i = 0; i < 8; ++i) {
            const int k = s * 32 + h2 * 8 + i;
            const int kh = k >> 4, inner = k & 15;
            float v = 0.0f;
            if (inner < 15 && k < 80) {
                const int kw = inner / 3;
                const int c  = inner - kw * 3;
                v = w_mu[((kh * 5 + kw) * 3 + c) * KOUT + ch];
            }
            r[i] = f2bf(v);
        }
        wf[f] = r;
    }
    if (t < KOUT) wsg[t] = softplus_hw(w_sigma[t]);

    // ---- KL scalar ----
    float s = 0.0f;
    for (int i = t; i < RK * RK * CIN * KOUT; i += 256) {
        const float v = w_mu[i];
        s = fmaf(v, v, s);
    }
    float u = s * (100.0f / 4800.0f);
    if (t < KOUT) {
        const float wsv = w_sigma[t];
        u += (-wsv + softplus_hw(wsv) * 100.0f) * (1.0f / 64.0f);
    }
    #pragma unroll
    for (int off = 32; off > 0; off >>= 1)
        u += __shfl_down(u, off, 64);
    if ((t & 63) == 0) red[t >> 6] = u;
    __syncthreads();
    if (t == 0) {
        const float U = red[0] + red[1] + red[2] + red[3];
        out[2 * NTOT] = 0.5f * (-4.6051701860f - 1.0f + U);
    }
}

// ---- conv: block = 16 rows x 32 px; wave = 4 rows; frags in VGPR ----
__global__ __launch_bounds__(256, 4) void vdp_conv_kernel(
    const float* __restrict__ mu_in, const void* __restrict__ ws, float* __restrict__ out)
{
    __shared__ float s_row[PATCH_H][SROW_F];     // 20 x 112 f32 (8.75 KB)
    __shared__ float s_ssq[PATCH_H][40];         // sum_c x^2, 36 valid (3.2 KB)
    __shared__ float s_sq[TH][TW];               // 5x5 box mean (2 KB)

    const int tid  = threadIdx.x;
    const int lane = tid & 63;
    const int wid  = tid >> 6;
    const int p    = lane & 15;            // MFMA: pixel col; sigma: ch-group kg
    const int h2   = lane >> 4;            // MFMA: k subgroup;  sigma: px-in-quad

    const int b = blockIdx.z;
    int ho0 = blockIdx.y * TH; if (ho0 > HOUT - TH) ho0 = HOUT - TH;  // 204 (overlap recompute)
    int wo0 = blockIdx.x * TW; if (wo0 > WOUT - TW) wo0 = WOUT - TW;  // 188

    // ---- weight frags (L2/L3-hot, coalesced) + sigma scale ----
    const short8* wfg = (const short8*)ws;
    short8 wf[12];
    #pragma unroll
    for (int f = 0; f < 12; ++f) wf[f] = wfg[f * 64 + lane];
    const float* wsg_g = (const float*)((const char*)ws + WS_WSG_OFF);
    const v4f wsg_kg = *(const v4f*)(wsg_g + p * 4);   // sigma: ch = 4*kg..+3

    // ---- stage 20 input rows x 108 floats (cols 108..111 zeroed) ----
    const size_t inbase = ((size_t)b * HIN + ho0) * (WIN * CIN) + wo0 * CIN;
    for (int idx = tid; idx < PATCH_H * SROW_F; idx += 256) {
        const int r = idx / SROW_F, c = idx - r * SROW_F;
        float v = 0.0f;
        if (c < PATCH_W * CIN) v = mu_in[inbase + (size_t)r * (WIN * CIN) + c];
        s_row[r][c] = v;
    }
    __syncthreads();

    // ---- per-pixel channel-summed squares (20 x 36) ----
    for (int idx = tid; idx < PATCH_H * PATCH_W; idx += 256) {
        const int r = idx / PATCH_W, px = idx - r * PATCH_W;
        const float a0 = s_row[r][3 * px], a1 = s_row[r][3 * px + 1], a2 = s_row[r][3 * px + 2];
        s_ssq[r][px] = fmaf(a0, a0, fmaf(a1, a1, a2 * a2));
    }
    __syncthreads();

    // ---- 5x5 box mean (16 x 32, two full passes of 256 threads) ----
    #pragma unroll
    for (int h = 0; h < 2; ++h) {
        const int orow = (tid >> 5) + h * 8, pc = tid & 31;
        float a = 0.0f;
        #pragma unroll
        for (int kh = 0; kh < RK; ++kh)
            #pragma unroll
            for (int kw = 0; kw < RK; ++kw)
                a += s_ssq[orow + kh][pc + kw];
        s_sq[orow][pc] = a * (1.0f / 75.0f);
    }
    __syncthreads();

    // ---- main: wave = 4 output rows x 32 px x 64 ch ----
    #pragma unroll 1
    for (int j = 0; j < 4; ++j) {
        const int rt = (wid << 2) | j;
        const size_t rowbase = (((size_t)b * HOUT + ho0 + rt) * WOUT + wo0) * KOUT;

        // two 16-px groups, sequential (keeps acc footprint at 16 VGPR)
        #pragma unroll
        for (int g = 0; g < 2; ++g) {
            short8 pf[3];
            #pragma unroll
            for (int s = 0; s < 3; ++s) {
                int ridx = rt + 2 * s + (h2 >> 1);
                ridx = ridx > PATCH_H - 1 ? PATCH_H - 1 : ridx;   // k>=80 pad: value x 0-weight
                const float* rp = &s_row[ridx][3 * (16 * g + p) + 8 * (h2 & 1)];
                short8 r;
                #pragma unroll
                for (int i = 0; i < 8; ++i) r[i] = f2bf(rp[i]);
                pf[s] = r;
            }
            v4f acc[4];
            #pragma unroll
            for (int nb = 0; nb < 4; ++nb) {
                v4f a = {0.0f, 0.0f, 0.0f, 0.0f};
                #pragma unroll
                for (int s = 0; s < 3; ++s)
                    a = __builtin_amdgcn_mfma_f32_16x16x32_bf16(wf[s * 4 + nb], pf[s], a, 0, 0, 0);
                acc[nb] = a;
            }
            // mu: D col = pixel, rows = 4 ch at nb*16 + h2*4 (sector-complete stores)
            float* mp = out + rowbase + (size_t)(16 * g + p) * KOUT + h2 * 4;
            #pragma unroll
            for (int nb = 0; nb < 4; ++nb)
                *(v4f*)(mp + nb * 16) = acc[nb];
        }

        // sigma: 8 quads of 4 px -> contiguous 1KB wave-stores (8 KB per row)
        float* sp = out + NTOT + rowbase + p * 4;   // p = kg here
        #pragma unroll
        for (int q = 0; q < 8; ++q) {
            const int px = (q << 2) | h2;
            const float sq = s_sq[rt][px];
            v4f sg;
            sg.x = softplus_pos(wsg_kg.x * sq);
            sg.y = softplus_pos(wsg_kg.y * sq);
            sg.z = softplus_pos(wsg_kg.z * sq);
            sg.w = softplus_pos(wsg_kg.w * sq);
            *(v4f*)(sp + (size_t)px * KOUT) = sg;
        }
    }
}

extern "C" void kernel_launch(void* const* d_in, const int* in_sizes, int n_in,
                              void* d_out, int out_size, void* d_ws, size_t ws_size,
                              hipStream_t stream)
{
    (void)in_sizes; (void)n_in; (void)ws_size; (void)out_size;
    const float* mu_in   = (const float*)d_in[0];
    const float* w_mu    = (const float*)d_in[1];
    const float* w_sigma = (const float*)d_in[2];
    float* out = (float*)d_out;

    vdp_prep_kernel<<<1, 256, 0, stream>>>(w_mu, w_sigma, d_ws, out);
    dim3 grid((WOUT + TW - 1) / TW, (HOUT + TH - 1) / TH, BATCH);  // 7 x 14 x 32 = 3136
    vdp_conv_kernel<<<grid, 256, 0, stream>>>(mu_in, d_ws, out);
}